// Round 8
// baseline (395.192 us; speedup 1.0000x reference)
//
#include <hip/hip_runtime.h>
#include <hip/hip_bf16.h>
#include <hip/hip_fp16.h>
#include <type_traits>

typedef _Float16 f16;
typedef __attribute__((ext_vector_type(8))) _Float16 f16x8;
typedef __attribute__((ext_vector_type(4))) float floatx4;

#define B_ 4
#define T_ 2048
#define D_ 1024

// ws layout (bytes); total need = 106,954,752
#define XB_OFF   0ul          // f16 x: 16 MB ; reused as Vt after QKV GEMM
#define WB_OFF   16777216ul   // f16 W concat (3072x1024): 6 MB
#define QKV_OFF  23068672ul   // f16 qkv (8192x3072): 48 MB
#define S_OFF    73400320ul   // f16 S (4x2048x2048): 32 MB
#define VT_OFF   0ul          // f16 Vt (4x1024x2048): 16 MB (overwrites xb)

// async global->LDS, 16B per lane; lds dest = wave-uniform base + lane*16
#define ASYNC16(gp, lp) \
    __builtin_amdgcn_global_load_lds((const __attribute__((address_space(1))) unsigned int*)(gp), \
                                     (__attribute__((address_space(3))) unsigned int*)(lp), 16, 0, 0)

// ---------------- cast fp32 -> fp16 (x and the three W's) ----------------
__global__ __launch_bounds__(256) void cast_all(
    const float* __restrict__ x, const float* __restrict__ wq,
    const float* __restrict__ wk, const float* __restrict__ wv,
    f16* __restrict__ xb, f16* __restrict__ wb)
{
    long i = (long)blockIdx.x * 256 + threadIdx.x;   // group-of-4 index
    const float4* src; f16* dst;
    if (i < 2097152L)            { src = (const float4*)x;  dst = xb; }
    else if (i < 2359296L)       { i -= 2097152L; src = (const float4*)wq; dst = wb; }
    else if (i < 2621440L)       { i -= 2359296L; src = (const float4*)wk; dst = wb + 1048576; }
    else                         { i -= 2621440L; src = (const float4*)wv; dst = wb + 2097152; }
    float4 v = src[i];
    union { f16 h[4]; uint2 u; } o;
    o.h[0] = (f16)v.x; o.h[1] = (f16)v.y; o.h[2] = (f16)v.z; o.h[3] = (f16)v.w;
    ((uint2*)dst)[i] = o.u;
}

// ---------------- NT GEMM, BARRIER-FREE: C[m,n] = alpha*sum_k A[m,k]*B[n,k] ----
// Block 128x128, BK=32, 4 waves 2x2, wave tile 64x64, 16x16x32 MFMA.
// NO __syncthreads in the K-loop:
//   * A-fragments: per-lane global_load b128 straight to VGPRs (prefetch 1 iter
//     ahead; compiler emits precise vmcnt for the register dependency).
//   * B-tile: WAVE-PRIVATE LDS (4 KB/wave), double-buffered, filled by
//     global_load_lds. Only the owning wave reads it -> no cross-wave dep.
// RAW FIX (R7 failure): the DMA has no dest register, so the compiler CANNOT
// see the ds_read dependency. Explicit s_waitcnt vmcnt(12) before the
// ds_reads: ops younger than stageB(i)'s 4 DMAs are exactly loadA(i)(4) +
// stageB(i+1)(4) + loadA(i+1)(4) = 12, so vmcnt(12) == "buffer cur landed",
// while iter i+1's 8 prefetch ops stay in flight (vmcnt never 0).
// WAR is safe: bf reaches registers (lgkmcnt before MFMA) before the
// overwriting DMA of iter i+1 is issued in program order.
// imm 0xF7C = vmcnt(12), expcnt(7)=nowait, lgkmcnt(15)=nowait.
template <typename CT, int K>
__global__ __launch_bounds__(256) void gemm_nt(
    const f16* __restrict__ A, int lda, long sA,
    const f16* __restrict__ B, int ldb, long sB,
    CT* __restrict__ C, int ldc, long sC,
    float alpha)
{
    __shared__ f16 Bs[4][2][2048];   // [wave][buf][64 rows x 32 k] = 32 KB

    const int tid = threadIdx.x;
    const int m0 = blockIdx.y * 128;
    const int n0 = blockIdx.x * 128;
    const int bz = blockIdx.z;
    A += (long)bz * sA;
    B += (long)bz * sB;
    C += (long)bz * sC;

    const int w  = tid >> 6;
    const int l  = tid & 63;
    const int wm = (w >> 1) * 64;
    const int wn = (w & 1) * 64;
    const int lr = l & 15;                 // m (A) / n (B) within 16-tile
    const int kg = l >> 4;                 // k-group 0..3
    const int kx = kg ^ ((lr >> 1) & 3);   // swizzled LDS slab for reads

    floatx4 acc[4][4] = {};

    const long ldaL = lda, ldbL = ldb;
    // lane-private pointers
    const int gsl = (l & 3) ^ ((l >> 3) & 3);
    const f16* Bl  = B + (long)(n0 + wn + (l >> 2)) * ldbL + gsl * 8;  // DMA src
    const f16* Alp = A + (long)(m0 + wm + lr) * ldaL + kg * 8;         // A-frag src

    auto stageB = [&](int buf, int kk) {
        #pragma unroll
        for (int c = 0; c < 4; c++)
            ASYNC16(Bl + kk + c * 16 * ldbL, &Bs[w][buf][c * 512]);
    };
    auto loadA = [&](f16x8* af, int kk) {
        #pragma unroll
        for (int mi = 0; mi < 4; mi++)
            af[mi] = *(const f16x8*)(Alp + kk + (long)(mi * 16) * ldaL);
    };

    f16x8 afc[4], afn[4];
    stageB(0, 0);
    loadA(afc, 0);

    #pragma unroll 2
    for (int k0 = 0; k0 < K; k0 += 32) {
        const int buf = (k0 >> 5) & 1;
        if (k0 + 32 < K) {              // prefetch next tile (B-DMA first, then A)
            stageB(buf ^ 1, k0 + 32);
            loadA(afn, k0 + 32);
        }

        // drain this iter's B-DMAs (4 oldest); keep prefetch (8 ops) in flight
        __builtin_amdgcn_s_waitcnt(0xF7C);   // vmcnt(12)

        f16x8 bf[4];
        #pragma unroll
        for (int ni = 0; ni < 4; ni++)
            bf[ni] = *(const f16x8*)&Bs[w][buf][(ni * 16 + lr) * 32 + kx * 8];
        #pragma unroll
        for (int mi = 0; mi < 4; mi++)
            #pragma unroll
            for (int ni = 0; ni < 4; ni++)
                acc[mi][ni] = __builtin_amdgcn_mfma_f32_16x16x32_f16(afc[mi], bf[ni], acc[mi][ni], 0, 0, 0);

        #pragma unroll
        for (int mi = 0; mi < 4; mi++) afc[mi] = afn[mi];
    }

    // epilogue: C/D layout: col = lane&15, row = (lane>>4)*4 + reg
    #pragma unroll
    for (int mi = 0; mi < 4; mi++) {
        #pragma unroll
        for (int ni = 0; ni < 4; ni++) {
            #pragma unroll
            for (int r = 0; r < 4; r++) {
                int row = m0 + wm + mi * 16 + kg * 4 + r;
                int col = n0 + wn + ni * 16 + lr;
                float v = acc[mi][ni][r] * alpha;
                if constexpr (std::is_same<CT, float>::value)
                    C[(long)row * ldc + col] = v;
                else
                    C[(long)row * ldc + col] = (f16)v;
            }
        }
    }
}

// ---------------- transpose V (within qkv) -> Vt[b][d][j] ----------------
__global__ __launch_bounds__(256) void transpose_v(const f16* __restrict__ qkv, f16* __restrict__ vt)
{
    __shared__ f16 tile[32][33];
    int b  = blockIdx.z;
    int j0 = blockIdx.x * 32;
    int d0 = blockIdx.y * 32;
    int tx = threadIdx.x & 31;
    int ty = threadIdx.x >> 5;   // 0..7
    #pragma unroll
    for (int i = 0; i < 4; i++) {
        int j = j0 + ty + i * 8;
        tile[ty + i * 8][tx] = qkv[((long)b * T_ + j) * 3072 + 2048 + d0 + tx];
    }
    __syncthreads();
    #pragma unroll
    for (int i = 0; i < 4; i++) {
        int d = d0 + ty + i * 8;
        vt[((long)b * D_ + d) * T_ + j0 + tx] = tile[tx][ty + i * 8];
    }
}

// ---------------- row softmax: one wave per row, no barriers ----------------
__global__ __launch_bounds__(256) void softmax_rows(f16* __restrict__ S)
{
    long row = (long)blockIdx.x * 4 + (threadIdx.x >> 6);
    int l = threadIdx.x & 63;
    uint4* p4 = (uint4*)(S + row * 2048);
    union U { uint4 u; f16 h[8]; } d[4];
    float v[32];
    float mx = -1e30f;
    #pragma unroll
    for (int i = 0; i < 4; i++) {
        d[i].u = p4[i * 64 + l];
        #pragma unroll
        for (int j = 0; j < 8; j++) { v[i * 8 + j] = (float)d[i].h[j]; mx = fmaxf(mx, v[i * 8 + j]); }
    }
    #pragma unroll
    for (int off = 32; off; off >>= 1) mx = fmaxf(mx, __shfl_xor(mx, off, 64));
    float s = 0.f;
    #pragma unroll
    for (int i = 0; i < 32; i++) { v[i] = __expf(v[i] - mx); s += v[i]; }
    #pragma unroll
    for (int off = 32; off; off >>= 1) s += __shfl_xor(s, off, 64);
    float inv = 1.f / s;
    #pragma unroll
    for (int i = 0; i < 4; i++) {
        #pragma unroll
        for (int j = 0; j < 8; j++) d[i].h[j] = (f16)(v[i * 8 + j] * inv);
        p4[i * 64 + l] = d[i].u;
    }
}

// ---------------- launch ----------------
extern "C" void kernel_launch(void* const* d_in, const int* in_sizes, int n_in,
                              void* d_out, int out_size, void* d_ws, size_t ws_size,
                              hipStream_t stream)
{
    const float* x  = (const float*)d_in[0];
    const float* wq = (const float*)d_in[1];
    const float* wk = (const float*)d_in[2];
    const float* wv = (const float*)d_in[3];
    float* out = (float*)d_out;
    char* ws = (char*)d_ws;
    f16* xb  = (f16*)(ws + XB_OFF);
    f16* wb  = (f16*)(ws + WB_OFF);
    f16* qkv = (f16*)(ws + QKV_OFF);
    f16* s   = (f16*)(ws + S_OFF);
    f16* vt  = (f16*)(ws + VT_OFF);

    // 1) cast x, Wq, Wk, Wv to fp16 (Wb = [Wq;Wk;Wv] as 3072x1024)
    cast_all<<<11264, 256, 0, stream>>>(x, wq, wk, wv, xb, wb);

    // 2) QKV = xb @ Wb^T : M=8192, N=3072, K=1024, fp16 out
    gemm_nt<f16, 1024><<<dim3(24, 64, 1), 256, 0, stream>>>(
        xb, 1024, 0L, wb, 1024, 0L, qkv, 3072, 0L, 1.0f);

    // 3) Vt[b][d][j] = V[b][j][d]
    transpose_v<<<dim3(64, 32, 4), 256, 0, stream>>>(qkv, vt);

    // 4) S = (1/32) * Q @ K^T per batch : M=N=2048, K=1024
    gemm_nt<f16, 1024><<<dim3(16, 16, 4), 256, 0, stream>>>(
        qkv,        3072, (long)T_ * 3072,
        qkv + 1024, 3072, (long)T_ * 3072,
        s,          2048, (long)T_ * 2048, 0.03125f);

    // 5) softmax rows, in place (1 wave/row, 4 rows/block)
    softmax_rows<<<2048, 256, 0, stream>>>(s);

    // 6) O = P @ Vt^T per batch : M=2048, N=1024, K=2048, fp32 out -> d_out
    gemm_nt<float, 2048><<<dim3(8, 16, 4), 256, 0, stream>>>(
        s,  2048, (long)T_ * 2048,
        vt, 2048, (long)D_ * 2048,
        out, 1024, (long)T_ * 1024, 1.0f);
}